// Round 9
// baseline (1953.998 us; speedup 1.0000x reference)
//
#include <hip/hip_runtime.h>
#include <cmath>

#define NNODES 100000
#define NEDGES 1600000
#define INC 512
#define HC 256
#define NLAYERS 8

typedef _Float16 half8 __attribute__((ext_vector_type(8)));
typedef _Float16 half4v __attribute__((ext_vector_type(4)));
typedef float floatx4 __attribute__((ext_vector_type(4)));

typedef __attribute__((address_space(3))) unsigned int u32_lds;
typedef __attribute__((address_space(1))) unsigned int u32_glb;

struct __attribute__((aligned(8))) EdgeP { int s; float w; };

__device__ __forceinline__ EdgeP ldnt_edge(const EdgeP* p) {
  unsigned long long v = __builtin_nontemporal_load((const unsigned long long*)p);
  EdgeP e; __builtin_memcpy(&e, &v, 8); return e;
}
__device__ __forceinline__ half4v ldnt_h4(const _Float16* p) {
  unsigned long long v = __builtin_nontemporal_load((const unsigned long long*)p);
  half4v h; __builtin_memcpy(&h, &v, 8); return h;
}

// ---- edge dtype detection: int64 little-endian with values < 2^31 => odd 32-bit words all zero.
__global__ void k_detect(const unsigned int* __restrict__ eb, int* __restrict__ mode) {
  int lane = threadIdx.x;  // 64 threads
  unsigned v = eb[2 * lane + 1];
  unsigned long long nz = __ballot(v != 0u);
  if (lane == 0) *mode = (nz == 0ull) ? 1 : 0;
}

__device__ __forceinline__ int edge_at(const void* eb, int m, int i) {
  return m ? (int)((const long long*)eb)[i] : ((const int*)eb)[i];
}

// ---------------- CSR build (unchanged, green since R3) ----------------

__global__ __launch_bounds__(256) void k_zero2(int* __restrict__ a, int* __restrict__ b, int n) {
  int i = blockIdx.x * 256 + threadIdx.x;
  if (i < n) { a[i] = 0; b[i] = 0; }
}

__global__ __launch_bounds__(256) void k_count(const void* __restrict__ eb, const int* __restrict__ mode,
                                               int* __restrict__ counts) {
  int e = blockIdx.x * 256 + threadIdx.x;
  if (e >= NEDGES) return;
  int m = *mode;
  atomicAdd(&counts[edge_at(eb, m, NEDGES + e)], 1);
}

__global__ __launch_bounds__(256) void k_dinv(const int* __restrict__ counts, float* __restrict__ dinv) {
  int i = blockIdx.x * 256 + threadIdx.x;
  if (i < NNODES) dinv[i] = 1.0f / sqrtf((float)counts[i] + 1.0f);  // +1 self loop
}

__global__ __launch_bounds__(256) void k_scan1(const int* __restrict__ counts, int* __restrict__ rowptr,
                                               int* __restrict__ partials) {
  __shared__ int sm[256];
  int i = blockIdx.x * 256 + threadIdx.x;
  int v = (i < NNODES) ? counts[i] : 0;
  sm[threadIdx.x] = v;
  __syncthreads();
  for (int off = 1; off < 256; off <<= 1) {
    int u = (threadIdx.x >= off) ? sm[threadIdx.x - off] : 0;
    __syncthreads();
    sm[threadIdx.x] += u;
    __syncthreads();
  }
  if (i < NNODES) rowptr[i] = sm[threadIdx.x] - v;
  if (threadIdx.x == 255) partials[blockIdx.x] = sm[255];
}

__global__ __launch_bounds__(512) void k_scan2(int* __restrict__ partials, int* __restrict__ rowptr, int nb) {
  __shared__ int sm[512];
  int t = threadIdx.x;
  int v = (t < nb) ? partials[t] : 0;
  sm[t] = v;
  __syncthreads();
  for (int off = 1; off < 512; off <<= 1) {
    int u = (t >= off) ? sm[t - off] : 0;
    __syncthreads();
    sm[t] += u;
    __syncthreads();
  }
  if (t < nb) partials[t] = sm[t] - v;
  if (t == 0) rowptr[NNODES] = NEDGES;
}

__global__ __launch_bounds__(256) void k_scan3(int* __restrict__ rowptr, const int* __restrict__ partials) {
  int i = blockIdx.x * 256 + threadIdx.x;
  if (i < NNODES) rowptr[i] += partials[blockIdx.x];
}

__global__ __launch_bounds__(256) void k_fill(const void* __restrict__ eb, const int* __restrict__ mode,
                                              const int* __restrict__ rowptr,
                                              int* __restrict__ cursor, const float* __restrict__ dinv,
                                              EdgeP* __restrict__ ep) {
  int e = blockIdx.x * 256 + threadIdx.x;
  if (e >= NEDGES) return;
  int m = *mode;
  int r = edge_at(eb, m, e), c = edge_at(eb, m, NEDGES + e);
  int p = rowptr[c] + atomicAdd(&cursor[c], 1);
  EdgeP pr; pr.s = r; pr.w = dinv[r] * dinv[c];
  ep[p] = pr;
}

// ---------------- weight transposes to f16 ----------------
__global__ __launch_bounds__(256) void k_tr_wemb(const float* __restrict__ W, _Float16* __restrict__ WT) {
  int idx = blockIdx.x * 256 + threadIdx.x;        // 131072 = c*512 + k
  int k = idx & 511, c = idx >> 9;
  WT[idx] = (_Float16)W[k * 256 + c];
}
__global__ __launch_bounds__(256) void k_tr_wc(const float* __restrict__ W, _Float16* __restrict__ WT) {
  int idx = blockIdx.x * 256 + threadIdx.x;        // 524288 = l*65536 + n*256 + k
  int k = idx & 255, n = (idx >> 8) & 255, l = idx >> 16;
  WT[idx] = (_Float16)W[(l * 256 + k) * 256 + n];
}

// ---------------- embed: h0 = relu(x @ Wemb + b), global_load_lds-staged A ----------------
// Block 64 rows x 256 cols (4 waves, wave w owns cols w*64..+63). K=512, 16 steps of 32.
// A-tile [64][32] f32 double-buffered in LDS (2x8KB), staged via global_load_lds w=16.
// XOR swizzle (both-sides): stage source unit u = (L&7)^(row&7) with linear LDS dest L*16;
// ds_read at row*128 + (u^(row&7))*16 -> 2-way banks (free). Rows clamped (no OOB).
// Epilogue: two-pass Cl[32][264] f16 (union with staging bufs), coalesced half8 stores.

__global__ __launch_bounds__(256) void k_embed(const float* __restrict__ X,
                                               const _Float16* __restrict__ WT,   // [256][512] f16
                                               const float* __restrict__ bias,
                                               _Float16* __restrict__ outh, _Float16* __restrict__ outh2) {
  __shared__ char smem[16896];   // max(2*8192 staging, 32*264*2 Cl)
  int t = threadIdx.x;
  int wave = t >> 6, lane = t & 63;
  int r = lane & 15, g = lane >> 4;
  int row0 = blockIdx.x * 64;
  int c0 = wave * 64;

  floatx4 acc[4][4] = {};

  auto stage = [&](int buf, int ks) {
#pragma unroll
    for (int rd = 0; rd < 2; ++rd) {
      int L = rd * 256 + t;
      int row = L >> 3;
      int u = (L & 7) ^ (row & 7);
      int grow = row0 + row; if (grow >= NNODES) grow = NNODES - 1;
      const float* src = X + (size_t)grow * INC + ks + u * 4;
      char* dstbase = smem + buf * 8192 + (rd * 256 + wave * 64) * 16;  // wave-uniform
      __builtin_amdgcn_global_load_lds((const u32_glb*)src, (u32_lds*)dstbase, 16, 0, 0);
    }
  };

  auto compute = [&](int buf, int ks) {
    const char* bufp = smem + buf * 8192;
    half8 a[4], b[4];
#pragma unroll
    for (int rt = 0; rt < 4; ++rt) {
      int row = rt * 16 + r;
      int sw = row & 7;
      float4 f0 = *(const float4*)(bufp + row * 128 + ((2 * g) ^ sw) * 16);
      float4 f1 = *(const float4*)(bufp + row * 128 + ((2 * g + 1) ^ sw) * 16);
      a[rt] = half8{ (_Float16)f0.x, (_Float16)f0.y, (_Float16)f0.z, (_Float16)f0.w,
                     (_Float16)f1.x, (_Float16)f1.y, (_Float16)f1.z, (_Float16)f1.w };
    }
#pragma unroll
    for (int ct = 0; ct < 4; ++ct)
      b[ct] = *(const half8*)(WT + (size_t)(c0 + ct * 16 + r) * INC + ks + g * 8);
#pragma unroll
    for (int rt = 0; rt < 4; ++rt)
#pragma unroll
      for (int ct = 0; ct < 4; ++ct)
        acc[rt][ct] = __builtin_amdgcn_mfma_f32_16x16x32_f16(a[rt], b[ct], acc[rt][ct], 0, 0, 0);
  };

  stage(0, 0);
#pragma unroll 2
  for (int s = 0; s < 16; ++s) {
    if (s < 15) stage((s + 1) & 1, (s + 1) * 32);
    __syncthreads();
    compute(s & 1, s * 32);
    __syncthreads();
  }

  // epilogue: bias + relu, two half-tiles through Cl
  _Float16 (*Cl)[264] = (_Float16(*)[264])smem;
#pragma unroll
  for (int p = 0; p < 2; ++p) {
    __syncthreads();
#pragma unroll
    for (int rt2 = 0; rt2 < 2; ++rt2) {
      int rt = p * 2 + rt2;
#pragma unroll
      for (int q = 0; q < 4; ++q) {
        int lrow = rt2 * 16 + g * 4 + q;
#pragma unroll
        for (int ct = 0; ct < 4; ++ct) {
          int col = c0 + ct * 16 + r;
          float v = acc[rt][ct][q] + bias[col];
          v = fmaxf(v, 0.0f);
          Cl[lrow][col] = (_Float16)v;
        }
      }
    }
    __syncthreads();
    int lrow = t >> 3, cc = (t & 7) * 32;
    int grow = row0 + p * 32 + lrow;
    if (grow < NNODES) {
      size_t base = (size_t)grow * HC + cc;
#pragma unroll
      for (int i = 0; i < 4; ++i) {
        half8 v = *(const half8*)&Cl[lrow][cc + i * 8];
        *(half8*)(outh + base + i * 8) = v;
        *(half8*)(outh2 + base + i * 8) = v;
      }
    }
  }
}

// ---------------- fused layer (32-node tile), R8-green + nt hints ----------------
// nt loads on ep and h0 (streaming, re-read next layer sequentially) to stop them
// evicting the gather-hot h from L3. h gather + hn stores stay cached.

template <bool LAST>
__global__ __launch_bounds__(256) void k_layer(const _Float16* __restrict__ h,
                                               const _Float16* __restrict__ h0,
                                               const int* __restrict__ rowptr,
                                               const EdgeP* __restrict__ ep,
                                               const float* __restrict__ dinv,
                                               const _Float16* __restrict__ WT,
                                               float ob, float beta,
                                               _Float16* __restrict__ hn, float* __restrict__ outf) {
  __shared__ _Float16 M[32][264];
  int t = threadIdx.x;
  int wave = t >> 6, lane = t & 63;
  int row0 = blockIdx.x * 32;
  int c = lane * 4;

  // ---- phase 1: spmm + residual into M (8 nodes per wave)
  for (int i = 0; i < 8; ++i) {
    int lrow = wave * 8 + i;
    int node = row0 + lrow;
    if (node < NNODES) {
      size_t base = (size_t)node * HC + c;
      float di = dinv[node];
      float wsw = di * di;
      half4v hv = *(const half4v*)(h + base);
      float a0 = wsw * (float)hv[0], a1 = wsw * (float)hv[1];
      float a2 = wsw * (float)hv[2], a3 = wsw * (float)hv[3];
      int e = rowptr[node], en = rowptr[node + 1];
      for (; e + 7 < en; e += 8) {
        EdgeP p0 = ldnt_edge(ep + e),     p1 = ldnt_edge(ep + e + 1);
        EdgeP p2 = ldnt_edge(ep + e + 2), p3 = ldnt_edge(ep + e + 3);
        EdgeP p4 = ldnt_edge(ep + e + 4), p5 = ldnt_edge(ep + e + 5);
        EdgeP p6 = ldnt_edge(ep + e + 6), p7 = ldnt_edge(ep + e + 7);
        half4v x0 = *(const half4v*)(h + (size_t)p0.s * HC + c);
        half4v x1 = *(const half4v*)(h + (size_t)p1.s * HC + c);
        half4v x2 = *(const half4v*)(h + (size_t)p2.s * HC + c);
        half4v x3 = *(const half4v*)(h + (size_t)p3.s * HC + c);
        half4v x4 = *(const half4v*)(h + (size_t)p4.s * HC + c);
        half4v x5 = *(const half4v*)(h + (size_t)p5.s * HC + c);
        half4v x6 = *(const half4v*)(h + (size_t)p6.s * HC + c);
        half4v x7 = *(const half4v*)(h + (size_t)p7.s * HC + c);
        a0 += p0.w * (float)x0[0] + p1.w * (float)x1[0] + p2.w * (float)x2[0] + p3.w * (float)x3[0]
            + p4.w * (float)x4[0] + p5.w * (float)x5[0] + p6.w * (float)x6[0] + p7.w * (float)x7[0];
        a1 += p0.w * (float)x0[1] + p1.w * (float)x1[1] + p2.w * (float)x2[1] + p3.w * (float)x3[1]
            + p4.w * (float)x4[1] + p5.w * (float)x5[1] + p6.w * (float)x6[1] + p7.w * (float)x7[1];
        a2 += p0.w * (float)x0[2] + p1.w * (float)x1[2] + p2.w * (float)x2[2] + p3.w * (float)x3[2]
            + p4.w * (float)x4[2] + p5.w * (float)x5[2] + p6.w * (float)x6[2] + p7.w * (float)x7[2];
        a3 += p0.w * (float)x0[3] + p1.w * (float)x1[3] + p2.w * (float)x2[3] + p3.w * (float)x3[3]
            + p4.w * (float)x4[3] + p5.w * (float)x5[3] + p6.w * (float)x6[3] + p7.w * (float)x7[3];
      }
      for (; e + 3 < en; e += 4) {
        EdgeP p0 = ldnt_edge(ep + e),     p1 = ldnt_edge(ep + e + 1);
        EdgeP p2 = ldnt_edge(ep + e + 2), p3 = ldnt_edge(ep + e + 3);
        half4v x0 = *(const half4v*)(h + (size_t)p0.s * HC + c);
        half4v x1 = *(const half4v*)(h + (size_t)p1.s * HC + c);
        half4v x2 = *(const half4v*)(h + (size_t)p2.s * HC + c);
        half4v x3 = *(const half4v*)(h + (size_t)p3.s * HC + c);
        a0 += p0.w * (float)x0[0] + p1.w * (float)x1[0] + p2.w * (float)x2[0] + p3.w * (float)x3[0];
        a1 += p0.w * (float)x0[1] + p1.w * (float)x1[1] + p2.w * (float)x2[1] + p3.w * (float)x3[1];
        a2 += p0.w * (float)x0[2] + p1.w * (float)x1[2] + p2.w * (float)x2[2] + p3.w * (float)x3[2];
        a3 += p0.w * (float)x0[3] + p1.w * (float)x1[3] + p2.w * (float)x2[3] + p3.w * (float)x3[3];
      }
      for (; e < en; ++e) {
        EdgeP p0 = ldnt_edge(ep + e);
        half4v x0 = *(const half4v*)(h + (size_t)p0.s * HC + c);
        a0 += p0.w * (float)x0[0];
        a1 += p0.w * (float)x0[1];
        a2 += p0.w * (float)x0[2];
        a3 += p0.w * (float)x0[3];
      }
      half4v h0v = ldnt_h4(h0 + base);
      half4v mo = { (_Float16)(0.9f * a0 + 0.1f * (float)h0v[0]),
                    (_Float16)(0.9f * a1 + 0.1f * (float)h0v[1]),
                    (_Float16)(0.9f * a2 + 0.1f * (float)h0v[2]),
                    (_Float16)(0.9f * a3 + 0.1f * (float)h0v[3]) };
      *(half4v*)&M[lrow][c] = mo;
    } else {
      *(half4v*)&M[lrow][c] = half4v{ (_Float16)0, (_Float16)0, (_Float16)0, (_Float16)0 };
    }
  }
  __syncthreads();

  // ---- phase 2: dense from M (K = HC = 256, fully unrolled)
  int r = lane & 15, g = lane >> 4;
  int c0 = wave * 64;
  floatx4 acc[2][4] = {};
#pragma unroll
  for (int ks = 0; ks < HC; ks += 32) {
    half8 a[2], b[4];
    a[0] = *(const half8*)&M[r][ks + g * 8];
    a[1] = *(const half8*)&M[16 + r][ks + g * 8];
#pragma unroll
    for (int ct = 0; ct < 4; ++ct)
      b[ct] = *(const half8*)(WT + (size_t)(c0 + ct * 16 + r) * HC + ks + g * 8);
#pragma unroll
    for (int rt = 0; rt < 2; ++rt)
#pragma unroll
      for (int ct = 0; ct < 4; ++ct)
        acc[rt][ct] = __builtin_amdgcn_mfma_f32_16x16x32_f16(a[rt], b[ct], acc[rt][ct], 0, 0, 0);
  }
  __syncthreads();   // drain all A-frag LDS reads before epilogue overwrites M

  // ---- epilogue
#pragma unroll
  for (int rt = 0; rt < 2; ++rt) {
#pragma unroll
    for (int q = 0; q < 4; ++q) {
      int lrow = rt * 16 + g * 4 + q;
#pragma unroll
      for (int ct = 0; ct < 4; ++ct) {
        int col = c0 + ct * 16 + r;
        float v = ob * (float)M[lrow][col] + beta * acc[rt][ct][q];
        if constexpr (!LAST) {
          v = fmaxf(v, 0.0f);
          M[lrow][col] = (_Float16)v;     // thread-own (row,col): safe RAW
        } else {
          int row = row0 + lrow;
          if (row < NNODES) outf[(size_t)row * HC + col] = v;
        }
      }
    }
  }
  if constexpr (!LAST) {
    __syncthreads();
    int lrow = t >> 3, cc = (t & 7) * 32;   // 8 threads/row, 32 f16 each
    int grow = row0 + lrow;
    if (grow < NNODES) {
      size_t base = (size_t)grow * HC + cc;
#pragma unroll
      for (int i = 0; i < 4; ++i)
        *(half8*)(hn + base + i * 8) = *(const half8*)&M[lrow][cc + i * 8];
    }
  }
}

// ---------------- host ----------------

extern "C" void kernel_launch(void* const* d_in, const int* in_sizes, int n_in,
                              void* d_out, int out_size, void* d_ws, size_t ws_size,
                              hipStream_t stream) {
  const float* x = (const float*)d_in[0];
  const void* ei = d_in[1];                    // int32 or int64 — detected on device
  const float* wemb = (const float*)d_in[2];   // [512][256]
  const float* bemb = (const float*)d_in[3];
  const float* wc = (const float*)d_in[4];     // [8][256][256]
  (void)in_sizes; (void)n_in; (void)out_size; (void)ws_size;

  char* ws = (char*)d_ws;
  size_t o = 0;
  auto alloc = [&](size_t bytes) -> char* {
    char* p = ws + o;
    o = (o + bytes + 511) & ~(size_t)511;
    return p;
  };
  // total workspace ~118.2 MB (proven budget)
  _Float16* hh      = (_Float16*)alloc((size_t)NNODES * HC * 2);  // 51.2 MB
  _Float16* h0h     = (_Float16*)alloc((size_t)NNODES * HC * 2);  // 51.2 MB
  EdgeP*    ep      = (EdgeP*)alloc((size_t)NEDGES * 8);          // 12.8 MB
  _Float16* wembT   = (_Float16*)alloc((size_t)INC * HC * 2);     // 0.26 MB
  _Float16* wcT     = (_Float16*)alloc((size_t)NLAYERS * HC * HC * 2);  // 1.05 MB
  int*      counts  = (int*)alloc((size_t)NNODES * 4);
  int*      cursor  = (int*)alloc((size_t)NNODES * 4);
  int*      rowptr  = (int*)alloc((size_t)(NNODES + 1) * 4);
  float*    dinv    = (float*)alloc((size_t)NNODES * 4);
  int*      partials= (int*)alloc(2048);
  int*      mode    = (int*)alloc(256);
  _Float16* hd      = (_Float16*)d_out;        // f16 h ping-pong buffer in d_out

  const int NB = (NNODES + 255) / 256;        // 391
  const int GEMM_GRID = (NNODES + 63) / 64;   // 1563
  const int LAYER_GRID = (NNODES + 31) / 32;  // 3125

  k_detect<<<1, 64, 0, stream>>>((const unsigned int*)ei, mode);
  k_zero2<<<NB, 256, 0, stream>>>(counts, cursor, NNODES);
  k_tr_wemb<<<(INC * HC) / 256, 256, 0, stream>>>(wemb, wembT);
  k_tr_wc<<<(NLAYERS * HC * HC) / 256, 256, 0, stream>>>(wc, wcT);
  k_count<<<(NEDGES + 255) / 256, 256, 0, stream>>>(ei, mode, counts);
  k_dinv<<<NB, 256, 0, stream>>>(counts, dinv);
  k_scan1<<<NB, 256, 0, stream>>>(counts, rowptr, partials);
  k_scan2<<<1, 512, 0, stream>>>(partials, rowptr, NB);
  k_scan3<<<NB, 256, 0, stream>>>(rowptr, partials);
  k_fill<<<(NEDGES + 255) / 256, 256, 0, stream>>>(ei, mode, rowptr, cursor, dinv, ep);

  // h1 = relu(x @ Wemb + b) -> hd (d_out region) and h0h
  k_embed<<<GEMM_GRID, 256, 0, stream>>>(x, wembT, bemb, hd, h0h);

  // ping-pong: hd -> hh -> hd -> ... ; layer 8 (last) reads hh, writes f32 d_out
  _Float16* cur = hd;
  _Float16* nxt = hh;
  for (int l = 0; l < NLAYERS; ++l) {
    float beta = (float)log(0.5 / (double)(l + 1) + 1.0);
    float ob = 1.0f - beta;
    const _Float16* W = wcT + (size_t)l * HC * HC;
    if (l < NLAYERS - 1) {
      k_layer<false><<<LAYER_GRID, 256, 0, stream>>>(cur, h0h, rowptr, ep, dinv, W,
                                                     ob, beta, nxt, (float*)nullptr);
      _Float16* tmp = cur; cur = nxt; nxt = tmp;
    } else {
      // parity: after embed(cur=hd) + 7 swaps, cur == hh (ws) — safe to write f32 into d_out
      k_layer<true><<<LAYER_GRID, 256, 0, stream>>>(cur, h0h, rowptr, ep, dinv, W,
                                                    ob, beta, (_Float16*)nullptr, (float*)d_out);
    }
  }
}

// Round 10
// 1700.725 us; speedup vs baseline: 1.1489x; 1.1489x over previous
//
#include <hip/hip_runtime.h>
#include <cmath>

#define NNODES 100000
#define NEDGES 1600000
#define INC 512
#define HC 256
#define NLAYERS 8

typedef _Float16 half8 __attribute__((ext_vector_type(8)));
typedef _Float16 half4v __attribute__((ext_vector_type(4)));
typedef float floatx4 __attribute__((ext_vector_type(4)));

typedef __attribute__((address_space(3))) unsigned int u32_lds;
typedef __attribute__((address_space(1))) unsigned int u32_glb;

struct __attribute__((aligned(8))) EdgeP { int s; float w; };

// ---- edge dtype detection: int64 little-endian with values < 2^31 => odd 32-bit words all zero.
__global__ void k_detect(const unsigned int* __restrict__ eb, int* __restrict__ mode) {
  int lane = threadIdx.x;  // 64 threads
  unsigned v = eb[2 * lane + 1];
  unsigned long long nz = __ballot(v != 0u);
  if (lane == 0) *mode = (nz == 0ull) ? 1 : 0;
}

__device__ __forceinline__ int edge_at(const void* eb, int m, int i) {
  return m ? (int)((const long long*)eb)[i] : ((const int*)eb)[i];
}

// ---------------- CSR build (unchanged, green since R3) ----------------

__global__ __launch_bounds__(256) void k_zero2(int* __restrict__ a, int* __restrict__ b, int n) {
  int i = blockIdx.x * 256 + threadIdx.x;
  if (i < n) { a[i] = 0; b[i] = 0; }
}

__global__ __launch_bounds__(256) void k_count(const void* __restrict__ eb, const int* __restrict__ mode,
                                               int* __restrict__ counts) {
  int e = blockIdx.x * 256 + threadIdx.x;
  if (e >= NEDGES) return;
  int m = *mode;
  atomicAdd(&counts[edge_at(eb, m, NEDGES + e)], 1);
}

__global__ __launch_bounds__(256) void k_dinv(const int* __restrict__ counts, float* __restrict__ dinv) {
  int i = blockIdx.x * 256 + threadIdx.x;
  if (i < NNODES) dinv[i] = 1.0f / sqrtf((float)counts[i] + 1.0f);  // +1 self loop
}

__global__ __launch_bounds__(256) void k_scan1(const int* __restrict__ counts, int* __restrict__ rowptr,
                                               int* __restrict__ partials) {
  __shared__ int sm[256];
  int i = blockIdx.x * 256 + threadIdx.x;
  int v = (i < NNODES) ? counts[i] : 0;
  sm[threadIdx.x] = v;
  __syncthreads();
  for (int off = 1; off < 256; off <<= 1) {
    int u = (threadIdx.x >= off) ? sm[threadIdx.x - off] : 0;
    __syncthreads();
    sm[threadIdx.x] += u;
    __syncthreads();
  }
  if (i < NNODES) rowptr[i] = sm[threadIdx.x] - v;
  if (threadIdx.x == 255) partials[blockIdx.x] = sm[255];
}

__global__ __launch_bounds__(512) void k_scan2(int* __restrict__ partials, int* __restrict__ rowptr, int nb) {
  __shared__ int sm[512];
  int t = threadIdx.x;
  int v = (t < nb) ? partials[t] : 0;
  sm[t] = v;
  __syncthreads();
  for (int off = 1; off < 512; off <<= 1) {
    int u = (t >= off) ? sm[t - off] : 0;
    __syncthreads();
    sm[t] += u;
    __syncthreads();
  }
  if (t < nb) partials[t] = sm[t] - v;
  if (t == 0) rowptr[NNODES] = NEDGES;
}

__global__ __launch_bounds__(256) void k_scan3(int* __restrict__ rowptr, const int* __restrict__ partials) {
  int i = blockIdx.x * 256 + threadIdx.x;
  if (i < NNODES) rowptr[i] += partials[blockIdx.x];
}

__global__ __launch_bounds__(256) void k_fill(const void* __restrict__ eb, const int* __restrict__ mode,
                                              const int* __restrict__ rowptr,
                                              int* __restrict__ cursor, const float* __restrict__ dinv,
                                              EdgeP* __restrict__ ep) {
  int e = blockIdx.x * 256 + threadIdx.x;
  if (e >= NEDGES) return;
  int m = *mode;
  int r = edge_at(eb, m, e), c = edge_at(eb, m, NEDGES + e);
  int p = rowptr[c] + atomicAdd(&cursor[c], 1);
  EdgeP pr; pr.s = r; pr.w = dinv[r] * dinv[c];
  ep[p] = pr;
}

// ---------------- weight transposes to f16 ----------------
__global__ __launch_bounds__(256) void k_tr_wemb(const float* __restrict__ W, _Float16* __restrict__ WT) {
  int idx = blockIdx.x * 256 + threadIdx.x;        // 131072 = c*512 + k
  int k = idx & 511, c = idx >> 9;
  WT[idx] = (_Float16)W[k * 256 + c];
}
__global__ __launch_bounds__(256) void k_tr_wc(const float* __restrict__ W, _Float16* __restrict__ WT) {
  int idx = blockIdx.x * 256 + threadIdx.x;        // 524288 = l*65536 + n*256 + k
  int k = idx & 255, n = (idx >> 8) & 255, l = idx >> 16;
  WT[idx] = (_Float16)W[(l * 256 + k) * 256 + n];
}

// ---------------- embed (unchanged from R9, improved): h0 = relu(x @ Wemb + b) ----------------

__global__ __launch_bounds__(256) void k_embed(const float* __restrict__ X,
                                               const _Float16* __restrict__ WT,   // [256][512] f16
                                               const float* __restrict__ bias,
                                               _Float16* __restrict__ outh, _Float16* __restrict__ outh2) {
  __shared__ char smem[16896];   // max(2*8192 staging, 32*264*2 Cl)
  int t = threadIdx.x;
  int wave = t >> 6, lane = t & 63;
  int r = lane & 15, g = lane >> 4;
  int row0 = blockIdx.x * 64;
  int c0 = wave * 64;

  floatx4 acc[4][4] = {};

  auto stage = [&](int buf, int ks) {
#pragma unroll
    for (int rd = 0; rd < 2; ++rd) {
      int L = rd * 256 + t;
      int row = L >> 3;
      int u = (L & 7) ^ (row & 7);
      int grow = row0 + row; if (grow >= NNODES) grow = NNODES - 1;
      const float* src = X + (size_t)grow * INC + ks + u * 4;
      char* dstbase = smem + buf * 8192 + (rd * 256 + wave * 64) * 16;  // wave-uniform
      __builtin_amdgcn_global_load_lds((const u32_glb*)src, (u32_lds*)dstbase, 16, 0, 0);
    }
  };

  auto compute = [&](int buf, int ks) {
    const char* bufp = smem + buf * 8192;
    half8 a[4], b[4];
#pragma unroll
    for (int rt = 0; rt < 4; ++rt) {
      int row = rt * 16 + r;
      int sw = row & 7;
      float4 f0 = *(const float4*)(bufp + row * 128 + ((2 * g) ^ sw) * 16);
      float4 f1 = *(const float4*)(bufp + row * 128 + ((2 * g + 1) ^ sw) * 16);
      a[rt] = half8{ (_Float16)f0.x, (_Float16)f0.y, (_Float16)f0.z, (_Float16)f0.w,
                     (_Float16)f1.x, (_Float16)f1.y, (_Float16)f1.z, (_Float16)f1.w };
    }
#pragma unroll
    for (int ct = 0; ct < 4; ++ct)
      b[ct] = *(const half8*)(WT + (size_t)(c0 + ct * 16 + r) * INC + ks + g * 8);
#pragma unroll
    for (int rt = 0; rt < 4; ++rt)
#pragma unroll
      for (int ct = 0; ct < 4; ++ct)
        acc[rt][ct] = __builtin_amdgcn_mfma_f32_16x16x32_f16(a[rt], b[ct], acc[rt][ct], 0, 0, 0);
  };

  stage(0, 0);
#pragma unroll 2
  for (int s = 0; s < 16; ++s) {
    if (s < 15) stage((s + 1) & 1, (s + 1) * 32);
    __syncthreads();
    compute(s & 1, s * 32);
    __syncthreads();
  }

  // epilogue: bias + relu, two half-tiles through Cl
  _Float16 (*Cl)[264] = (_Float16(*)[264])smem;
#pragma unroll
  for (int p = 0; p < 2; ++p) {
    __syncthreads();
#pragma unroll
    for (int rt2 = 0; rt2 < 2; ++rt2) {
      int rt = p * 2 + rt2;
#pragma unroll
      for (int q = 0; q < 4; ++q) {
        int lrow = rt2 * 16 + g * 4 + q;
#pragma unroll
        for (int ct = 0; ct < 4; ++ct) {
          int col = c0 + ct * 16 + r;
          float v = acc[rt][ct][q] + bias[col];
          v = fmaxf(v, 0.0f);
          Cl[lrow][col] = (_Float16)v;
        }
      }
    }
    __syncthreads();
    int lrow = t >> 3, cc = (t & 7) * 32;
    int grow = row0 + p * 32 + lrow;
    if (grow < NNODES) {
      size_t base = (size_t)grow * HC + cc;
#pragma unroll
      for (int i = 0; i < 4; ++i) {
        half8 v = *(const half8*)&Cl[lrow][cc + i * 8];
        *(half8*)(outh + base + i * 8) = v;
        *(half8*)(outh2 + base + i * 8) = v;
      }
    }
  }
}

// ---------------- fused layer (32-node tile), half-wave gather ----------------
// Phase 1 redesign: each wave = 2 half-waves (32 lanes), each owning one node with
// 16 B/lane (half8, 8 ch). Per unroll-8 iteration a wave keeps 16 rows (16 KB) in
// flight — 2x R8/R9 depth, half the load instrs per byte. Edge tails handled
// branchlessly (clamped index + zeroed weight) so no divergent unroll branches.
// nt hints REVERTED (R9: +17 MB FETCH, +18 us/layer). Phase 2 / epilogue / M tile
// byte-identical to the green R7/R8 structure.

template <bool LAST>
__global__ __launch_bounds__(256) void k_layer(const _Float16* __restrict__ h,
                                               const _Float16* __restrict__ h0,
                                               const int* __restrict__ rowptr,
                                               const EdgeP* __restrict__ ep,
                                               const float* __restrict__ dinv,
                                               const _Float16* __restrict__ WT,
                                               float ob, float beta,
                                               _Float16* __restrict__ hn, float* __restrict__ outf) {
  __shared__ _Float16 M[32][264];
  int t = threadIdx.x;
  int wave = t >> 6, lane = t & 63;
  int half = lane >> 5;        // which node of the pair
  int lc = lane & 31;          // lane within half
  int c8 = lc * 8;             // 8-channel base
  int row0 = blockIdx.x * 32;

  // ---- phase 1: spmm + residual into M (2 nodes per wave-pass, 4 passes)
  for (int p = 0; p < 4; ++p) {
    int lrow = wave * 8 + p * 2 + half;
    int node = row0 + lrow;
    bool valid = node < NNODES;
    int cn = valid ? node : NNODES - 1;
    size_t base = (size_t)cn * HC + c8;
    float di = dinv[cn];
    float wsw = valid ? di * di : 0.0f;
    half8 hv = *(const half8*)(h + base);
    float acc[8];
#pragma unroll
    for (int j = 0; j < 8; ++j) acc[j] = wsw * (float)hv[j];
    int e = rowptr[cn];
    int en = valid ? rowptr[cn + 1] : e;
    for (; e < en; e += 8) {
#pragma unroll
      for (int k2 = 0; k2 < 8; ++k2) {
        int idx = e + k2;
        bool v2 = idx < en;
        EdgeP pk = ep[v2 ? idx : en - 1];
        float w = v2 ? pk.w : 0.0f;
        half8 x = *(const half8*)(h + (size_t)pk.s * HC + c8);
#pragma unroll
        for (int j = 0; j < 8; ++j) acc[j] += w * (float)x[j];
      }
    }
    half8 h0v = *(const half8*)(h0 + base);
    half8 mo;
#pragma unroll
    for (int j = 0; j < 8; ++j) mo[j] = (_Float16)(0.9f * acc[j] + 0.1f * (float)h0v[j]);
    if (valid) {
      *(half8*)&M[lrow][c8] = mo;
    } else {
      half8 z = {};
      *(half8*)&M[lrow][c8] = z;
    }
  }
  __syncthreads();

  // ---- phase 2: dense from M (K = HC = 256, fully unrolled)
  int r = lane & 15, g = lane >> 4;
  int c0 = wave * 64;
  floatx4 acc2[2][4] = {};
#pragma unroll
  for (int ks = 0; ks < HC; ks += 32) {
    half8 a[2], b[4];
    a[0] = *(const half8*)&M[r][ks + g * 8];
    a[1] = *(const half8*)&M[16 + r][ks + g * 8];
#pragma unroll
    for (int ct = 0; ct < 4; ++ct)
      b[ct] = *(const half8*)(WT + (size_t)(c0 + ct * 16 + r) * HC + ks + g * 8);
#pragma unroll
    for (int rt = 0; rt < 2; ++rt)
#pragma unroll
      for (int ct = 0; ct < 4; ++ct)
        acc2[rt][ct] = __builtin_amdgcn_mfma_f32_16x16x32_f16(a[rt], b[ct], acc2[rt][ct], 0, 0, 0);
  }
  __syncthreads();   // drain all A-frag LDS reads before epilogue overwrites M

  // ---- epilogue
#pragma unroll
  for (int rt = 0; rt < 2; ++rt) {
#pragma unroll
    for (int q = 0; q < 4; ++q) {
      int lrow = rt * 16 + g * 4 + q;
#pragma unroll
      for (int ct = 0; ct < 4; ++ct) {
        int col = c0 + ct * 16 + r;
        float v = ob * (float)M[lrow][col] + beta * acc2[rt][ct][q];
        if constexpr (!LAST) {
          v = fmaxf(v, 0.0f);
          M[lrow][col] = (_Float16)v;     // thread-own (row,col): safe RAW
        } else {
          int row = row0 + lrow;
          if (row < NNODES) outf[(size_t)row * HC + col] = v;
        }
      }
    }
  }
  if constexpr (!LAST) {
    __syncthreads();
    int lrow = t >> 3, cc = (t & 7) * 32;   // 8 threads/row, 32 f16 each
    int grow = row0 + lrow;
    if (grow < NNODES) {
      size_t base = (size_t)grow * HC + cc;
#pragma unroll
      for (int i = 0; i < 4; ++i)
        *(half8*)(hn + base + i * 8) = *(const half8*)&M[lrow][cc + i * 8];
    }
  }
}

// ---------------- host ----------------

extern "C" void kernel_launch(void* const* d_in, const int* in_sizes, int n_in,
                              void* d_out, int out_size, void* d_ws, size_t ws_size,
                              hipStream_t stream) {
  const float* x = (const float*)d_in[0];
  const void* ei = d_in[1];                    // int32 or int64 — detected on device
  const float* wemb = (const float*)d_in[2];   // [512][256]
  const float* bemb = (const float*)d_in[3];
  const float* wc = (const float*)d_in[4];     // [8][256][256]
  (void)in_sizes; (void)n_in; (void)out_size; (void)ws_size;

  char* ws = (char*)d_ws;
  size_t o = 0;
  auto alloc = [&](size_t bytes) -> char* {
    char* p = ws + o;
    o = (o + bytes + 511) & ~(size_t)511;
    return p;
  };
  // total workspace ~118.2 MB (proven budget)
  _Float16* hh      = (_Float16*)alloc((size_t)NNODES * HC * 2);  // 51.2 MB
  _Float16* h0h     = (_Float16*)alloc((size_t)NNODES * HC * 2);  // 51.2 MB
  EdgeP*    ep      = (EdgeP*)alloc((size_t)NEDGES * 8);          // 12.8 MB
  _Float16* wembT   = (_Float16*)alloc((size_t)INC * HC * 2);     // 0.26 MB
  _Float16* wcT     = (_Float16*)alloc((size_t)NLAYERS * HC * HC * 2);  // 1.05 MB
  int*      counts  = (int*)alloc((size_t)NNODES * 4);
  int*      cursor  = (int*)alloc((size_t)NNODES * 4);
  int*      rowptr  = (int*)alloc((size_t)(NNODES + 1) * 4);
  float*    dinv    = (float*)alloc((size_t)NNODES * 4);
  int*      partials= (int*)alloc(2048);
  int*      mode    = (int*)alloc(256);
  _Float16* hd      = (_Float16*)d_out;        // f16 h ping-pong buffer in d_out

  const int NB = (NNODES + 255) / 256;        // 391
  const int GEMM_GRID = (NNODES + 63) / 64;   // 1563
  const int LAYER_GRID = (NNODES + 31) / 32;  // 3125

  k_detect<<<1, 64, 0, stream>>>((const unsigned int*)ei, mode);
  k_zero2<<<NB, 256, 0, stream>>>(counts, cursor, NNODES);
  k_tr_wemb<<<(INC * HC) / 256, 256, 0, stream>>>(wemb, wembT);
  k_tr_wc<<<(NLAYERS * HC * HC) / 256, 256, 0, stream>>>(wc, wcT);
  k_count<<<(NEDGES + 255) / 256, 256, 0, stream>>>(ei, mode, counts);
  k_dinv<<<NB, 256, 0, stream>>>(counts, dinv);
  k_scan1<<<NB, 256, 0, stream>>>(counts, rowptr, partials);
  k_scan2<<<1, 512, 0, stream>>>(partials, rowptr, NB);
  k_scan3<<<NB, 256, 0, stream>>>(rowptr, partials);
  k_fill<<<(NEDGES + 255) / 256, 256, 0, stream>>>(ei, mode, rowptr, cursor, dinv, ep);

  // h1 = relu(x @ Wemb + b) -> hd (d_out region) and h0h
  k_embed<<<GEMM_GRID, 256, 0, stream>>>(x, wembT, bemb, hd, h0h);

  // ping-pong: hd -> hh -> hd -> ... ; layer 8 (last) reads hh, writes f32 d_out
  _Float16* cur = hd;
  _Float16* nxt = hh;
  for (int l = 0; l < NLAYERS; ++l) {
    float beta = (float)log(0.5 / (double)(l + 1) + 1.0);
    float ob = 1.0f - beta;
    const _Float16* W = wcT + (size_t)l * HC * HC;
    if (l < NLAYERS - 1) {
      k_layer<false><<<LAYER_GRID, 256, 0, stream>>>(cur, h0h, rowptr, ep, dinv, W,
                                                     ob, beta, nxt, (float*)nullptr);
      _Float16* tmp = cur; cur = nxt; nxt = tmp;
    } else {
      // parity: after embed(cur=hd) + 7 swaps, cur == hh (ws) — safe to write f32 into d_out
      k_layer<true><<<LAYER_GRID, 256, 0, stream>>>(cur, h0h, rowptr, ep, dinv, W,
                                                    ob, beta, (_Float16*)nullptr, (float*)d_out);
    }
  }
}